// Round 1
// baseline (562.679 us; speedup 1.0000x reference)
//
#include <hip/hip_runtime.h>
#include <hip/hip_bf16.h>
#include <math.h>

#define N_NODES 50000
#define N_EDGES 800000
#define IN_DIM 128
#define HID 64
#define HEADS 4

// ---------------- tiled fp32 GEMM: C[M,NC] = A[M,K] * B[K,NC] ----------------
template<int K, int NC>
__global__ __launch_bounds__(256) void gemm64(const float* __restrict__ A,
                                              const float* __restrict__ B,
                                              float* __restrict__ C, int M) {
  constexpr int BK = 32;
  __shared__ float As[BK][65];   // transposed A tile, padded to kill bank conflicts
  __shared__ float Bs[BK][64];
  const int tid = threadIdx.x;
  const int m0 = blockIdx.x * 64;
  const int n0 = blockIdx.y * 64;
  const int ty = tid >> 4, tx = tid & 15;
  float acc[4][4] = {};
  const int arow = tid >> 3;        // 0..31
  const int akc  = (tid & 7) * 4;   // 0,4,...,28
  const int bkr  = tid >> 4;        // 0..15
  const int bc   = (tid & 15) * 4;  // 0,4,...,60

  for (int k0 = 0; k0 < K; k0 += BK) {
    #pragma unroll
    for (int j = 0; j < 2; ++j) {
      int r = arow + j * 32;
      float4 a = make_float4(0.f, 0.f, 0.f, 0.f);
      if (m0 + r < M) a = *(const float4*)&A[(size_t)(m0 + r) * K + k0 + akc];
      As[akc + 0][r] = a.x; As[akc + 1][r] = a.y;
      As[akc + 2][r] = a.z; As[akc + 3][r] = a.w;
    }
    #pragma unroll
    for (int j = 0; j < 2; ++j) {
      int kr = bkr + j * 16;
      *(float4*)&Bs[kr][bc] = *(const float4*)&B[(size_t)(k0 + kr) * NC + n0 + bc];
    }
    __syncthreads();
    #pragma unroll
    for (int k = 0; k < BK; ++k) {
      float a_[4], b_[4];
      #pragma unroll
      for (int i = 0; i < 4; ++i) a_[i] = As[k][ty * 4 + i];
      float4 b4 = *(const float4*)&Bs[k][tx * 4];
      b_[0] = b4.x; b_[1] = b4.y; b_[2] = b4.z; b_[3] = b4.w;
      #pragma unroll
      for (int i = 0; i < 4; ++i)
        #pragma unroll
        for (int j = 0; j < 4; ++j)
          acc[i][j] = fmaf(a_[i], b_[j], acc[i][j]);
    }
    __syncthreads();
  }
  #pragma unroll
  for (int i = 0; i < 4; ++i) {
    int r = m0 + ty * 4 + i;
    if (r < M) {
      float4 o4 = make_float4(acc[i][0], acc[i][1], acc[i][2], acc[i][3]);
      *(float4*)&C[(size_t)r * NC + n0 + tx * 4] = o4;
    }
  }
}

// ---------------- el/er: per-node attention dot products ----------------
template<int HD>
__global__ void eler_k(const float* __restrict__ ft, const float* __restrict__ al,
                       const float* __restrict__ ar, float* __restrict__ el,
                       float* __restrict__ er) {
  int n = blockIdx.x;
  int t = threadIdx.x;
  float f = ft[(size_t)n * HD + t];
  float vl = f * al[t], vr = f * ar[t];
  #pragma unroll
  for (int s = 32; s; s >>= 1) { vl += __shfl_down(vl, s); vr += __shfl_down(vr, s); }
  if ((t & 63) == 0) {
    int h = t >> 6;
    el[n * (HD / 64) + h] = vl;
    er[n * (HD / 64) + h] = vr;
  }
}

// ---------------- CSR build (histogram + scan + place) ----------------
__global__ void hist_k(const int* __restrict__ dst, int* __restrict__ cnt) {
  int e = blockIdx.x * 256 + threadIdx.x;
  if (e < N_EDGES) atomicAdd(&cnt[dst[e]], 1);
}

__global__ void scan1_k(const int* __restrict__ cnt, int* __restrict__ off,
                        int* __restrict__ bsum) {
  __shared__ int lds[1024];
  int tid = threadIdx.x;
  int i = blockIdx.x * 1024 + tid;
  int v = (i < N_NODES) ? cnt[i] : 0;
  lds[tid] = v;
  __syncthreads();
  for (int s = 1; s < 1024; s <<= 1) {
    int t = (tid >= s) ? lds[tid - s] : 0;
    __syncthreads();
    lds[tid] += t;
    __syncthreads();
  }
  if (i < N_NODES) off[i] = lds[tid] - v;  // exclusive
  if (tid == 1023) bsum[blockIdx.x] = lds[1023];
}

__global__ void scan2_k(int* __restrict__ bsum, int nb) {
  int lane = threadIdx.x;
  int v = (lane < nb) ? bsum[lane] : 0;
  int orig = v;
  for (int s = 1; s < 64; s <<= 1) { int t = __shfl_up(v, s); if (lane >= s) v += t; }
  if (lane < nb) bsum[lane] = v - orig;  // exclusive block bases
}

__global__ void scan3_k(int* __restrict__ off, const int* __restrict__ bsum) {
  int i = blockIdx.x * 1024 + threadIdx.x;
  if (i < N_NODES) off[i] += bsum[blockIdx.x];
  if (i == 0) off[N_NODES] = N_EDGES;
}

__global__ void place_k(const int* __restrict__ src, const int* __restrict__ dst,
                        const int* __restrict__ off, int* __restrict__ cnt,
                        int* __restrict__ ssrc) {
  int e = blockIdx.x * 256 + threadIdx.x;
  if (e < N_EDGES) {
    int d = dst[e];
    int p = atomicAdd(&cnt[d], 1);
    ssrc[off[d] + p] = src[e];
  }
}

// ---------------- per-node aggregation: softmax-weighted sum, bias, elu ----------------
// out[n,h,d] = elu( (sum_e exp(lrelu(el[src]+er[n]) - m) * ft[src,h,d]) / sum_e exp(...) + bias )
template<int H>
__global__ void agg_k(const float* __restrict__ ft, const float* __restrict__ el,
                      const float* __restrict__ er, const int* __restrict__ off,
                      const int* __restrict__ ssrc, const float* __restrict__ bias,
                      float* __restrict__ out) {
  constexpr int HD = H * 64;
  int n = blockIdx.x;
  int t = threadIdx.x;
  int w = t >> 6, lane = t & 63;
  int s0 = off[n], s1 = off[n + 1];
  float erv = er[n * H + w];
  float m = -INFINITY;
  for (int i = s0; i < s1; ++i) {
    int s = ssrc[i];
    float x = el[s * H + w] + erv;
    x = (x > 0.f) ? x : 0.01f * x;
    m = fmaxf(m, x);
  }
  float acc = 0.f, ssum = 0.f;
  for (int i = s0; i < s1; ++i) {
    int s = ssrc[i];
    float x = el[s * H + w] + erv;
    x = (x > 0.f) ? x : 0.01f * x;
    float ex = __expf(x - m);
    ssum += ex;
    acc = fmaf(ex, ft[(size_t)s * HD + w * 64 + lane], acc);
  }
  float o = (s1 > s0) ? acc / ssum : 0.f;
  o += bias[w * 64 + lane];
  o = (o > 0.f) ? o : expm1f(o);
  out[(size_t)n * HD + t] = o;
}

extern "C" void kernel_launch(void* const* d_in, const int* in_sizes, int n_in,
                              void* d_out, int out_size, void* d_ws, size_t ws_size,
                              hipStream_t stream) {
  const float* x   = (const float*)d_in[0];
  const int*   src = (const int*)d_in[1];
  const int*   dst = (const int*)d_in[2];
  const float* W1  = (const float*)d_in[3];
  const float* al1 = (const float*)d_in[4];
  const float* ar1 = (const float*)d_in[5];
  const float* b1  = (const float*)d_in[6];
  const float* W2  = (const float*)d_in[7];
  const float* al2 = (const float*)d_in[8];
  const float* ar2 = (const float*)d_in[9];
  const float* b2  = (const float*)d_in[10];
  float* out = (float*)d_out;

  char* ws = (char*)d_ws;
  size_t wo = 0;
  auto alloc = [&](size_t b) { void* p = ws + wo; wo = (wo + b + 255) & ~(size_t)255; return p; };
  float* ft1 = (float*)alloc((size_t)N_NODES * 256 * 4);
  float* h1  = (float*)alloc((size_t)N_NODES * 256 * 4);
  float* el1 = (float*)alloc((size_t)N_NODES * 4 * 4);
  float* er1 = (float*)alloc((size_t)N_NODES * 4 * 4);
  int*   off = (int*)alloc((size_t)(N_NODES + 1) * 4);
  int*   cnt = (int*)alloc((size_t)N_NODES * 4);
  int*   bsum= (int*)alloc(256);
  int*   ssrc= (int*)alloc((size_t)N_EDGES * 4);
  float* ft2 = ft1;            // ft1 dead after agg1 -> reuse
  float* el2 = el1, *er2 = er1;

  // ---- CSR by dst (once; same graph both layers) ----
  hipMemsetAsync(cnt, 0, (size_t)N_NODES * 4, stream);
  hist_k<<<(N_EDGES + 255) / 256, 256, 0, stream>>>(dst, cnt);
  int nb = (N_NODES + 1023) / 1024;
  scan1_k<<<nb, 1024, 0, stream>>>(cnt, off, bsum);
  scan2_k<<<1, 64, 0, stream>>>(bsum, nb);
  scan3_k<<<nb, 1024, 0, stream>>>(off, bsum);
  hipMemsetAsync(cnt, 0, (size_t)N_NODES * 4, stream);
  place_k<<<(N_EDGES + 255) / 256, 256, 0, stream>>>(src, dst, off, cnt, ssrc);

  // ---- layer 1 (H=4, D=64) ----
  gemm64<IN_DIM, 256><<<dim3((N_NODES + 63) / 64, 4), 256, 0, stream>>>(x, W1, ft1, N_NODES);
  eler_k<256><<<N_NODES, 256, 0, stream>>>(ft1, al1, ar1, el1, er1);
  agg_k<4><<<N_NODES, 256, 0, stream>>>(ft1, el1, er1, off, ssrc, b1, h1);

  // ---- layer 2 (H=1, D=64) ----
  gemm64<256, HID><<<dim3((N_NODES + 63) / 64, 1), 256, 0, stream>>>(h1, W2, ft2, N_NODES);
  eler_k<64><<<N_NODES, 64, 0, stream>>>(ft2, al2, ar2, el2, er2);
  agg_k<1><<<N_NODES, 64, 0, stream>>>(ft2, el2, er2, off, ssrc, b2, out);
}

// Round 2
// 460.165 us; speedup vs baseline: 1.2228x; 1.2228x over previous
//
#include <hip/hip_runtime.h>
#include <hip/hip_bf16.h>
#include <math.h>

#define N_NODES 50000
#define N_EDGES 800000
#define IN_DIM 128
#define HID 64
#define HEADS 4

// ---------------- tiled fp32 GEMM: C[M,NC] = A[M,K] * B[K,NC] ----------------
template<int K, int NC>
__global__ __launch_bounds__(256) void gemm64(const float* __restrict__ A,
                                              const float* __restrict__ B,
                                              float* __restrict__ C, int M) {
  constexpr int BK = 32;
  __shared__ float As[BK][65];
  __shared__ float Bs[BK][64];
  const int tid = threadIdx.x;
  const int m0 = blockIdx.x * 64;
  const int n0 = blockIdx.y * 64;
  const int ty = tid >> 4, tx = tid & 15;
  float acc[4][4] = {};
  const int arow = tid >> 3;
  const int akc  = (tid & 7) * 4;
  const int bkr  = tid >> 4;
  const int bc   = (tid & 15) * 4;

  for (int k0 = 0; k0 < K; k0 += BK) {
    #pragma unroll
    for (int j = 0; j < 2; ++j) {
      int r = arow + j * 32;
      float4 a = make_float4(0.f, 0.f, 0.f, 0.f);
      if (m0 + r < M) a = *(const float4*)&A[(size_t)(m0 + r) * K + k0 + akc];
      As[akc + 0][r] = a.x; As[akc + 1][r] = a.y;
      As[akc + 2][r] = a.z; As[akc + 3][r] = a.w;
    }
    #pragma unroll
    for (int j = 0; j < 2; ++j) {
      int kr = bkr + j * 16;
      *(float4*)&Bs[kr][bc] = *(const float4*)&B[(size_t)(k0 + kr) * NC + n0 + bc];
    }
    __syncthreads();
    #pragma unroll
    for (int k = 0; k < BK; ++k) {
      float a_[4], b_[4];
      #pragma unroll
      for (int i = 0; i < 4; ++i) a_[i] = As[k][ty * 4 + i];
      float4 b4 = *(const float4*)&Bs[k][tx * 4];
      b_[0] = b4.x; b_[1] = b4.y; b_[2] = b4.z; b_[3] = b4.w;
      #pragma unroll
      for (int i = 0; i < 4; ++i)
        #pragma unroll
        for (int j = 0; j < 4; ++j)
          acc[i][j] = fmaf(a_[i], b_[j], acc[i][j]);
    }
    __syncthreads();
  }
  #pragma unroll
  for (int i = 0; i < 4; ++i) {
    int r = m0 + ty * 4 + i;
    if (r < M) {
      float4 o4 = make_float4(acc[i][0], acc[i][1], acc[i][2], acc[i][3]);
      *(float4*)&C[(size_t)r * NC + n0 + tx * 4] = o4;
    }
  }
}

// ---------------- el/er: per-node attention dot products ----------------
template<int HD>
__global__ void eler_k(const float* __restrict__ ft, const float* __restrict__ al,
                       const float* __restrict__ ar, float* __restrict__ el,
                       float* __restrict__ er) {
  int n = blockIdx.x;
  int t = threadIdx.x;
  float f = ft[(size_t)n * HD + t];
  float vl = f * al[t], vr = f * ar[t];
  #pragma unroll
  for (int s = 32; s; s >>= 1) { vl += __shfl_down(vl, s); vr += __shfl_down(vr, s); }
  if ((t & 63) == 0) {
    int h = t >> 6;
    el[n * (HD / 64) + h] = vl;
    er[n * (HD / 64) + h] = vr;
  }
}

// ---------------- CSR build (histogram + scan + place) ----------------
__global__ void hist_k(const int* __restrict__ dst, int* __restrict__ cnt) {
  int e = blockIdx.x * 256 + threadIdx.x;
  if (e < N_EDGES) atomicAdd(&cnt[dst[e]], 1);
}

__global__ void scan1_k(const int* __restrict__ cnt, int* __restrict__ off,
                        int* __restrict__ bsum) {
  __shared__ int lds[1024];
  int tid = threadIdx.x;
  int i = blockIdx.x * 1024 + tid;
  int v = (i < N_NODES) ? cnt[i] : 0;
  lds[tid] = v;
  __syncthreads();
  for (int s = 1; s < 1024; s <<= 1) {
    int t = (tid >= s) ? lds[tid - s] : 0;
    __syncthreads();
    lds[tid] += t;
    __syncthreads();
  }
  if (i < N_NODES) off[i] = lds[tid] - v;
  if (tid == 1023) bsum[blockIdx.x] = lds[1023];
}

__global__ void scan2_k(int* __restrict__ bsum, int nb) {
  int lane = threadIdx.x;
  int v = (lane < nb) ? bsum[lane] : 0;
  int orig = v;
  for (int s = 1; s < 64; s <<= 1) { int t = __shfl_up(v, s); if (lane >= s) v += t; }
  if (lane < nb) bsum[lane] = v - orig;
}

__global__ void scan3_k(int* __restrict__ off, const int* __restrict__ bsum) {
  int i = blockIdx.x * 1024 + threadIdx.x;
  if (i < N_NODES) off[i] += bsum[blockIdx.x];
  if (i == 0) off[N_NODES] = N_EDGES;
}

__global__ void place_k(const int* __restrict__ src, const int* __restrict__ dst,
                        const int* __restrict__ off, int* __restrict__ cnt,
                        int* __restrict__ ssrc) {
  int e = blockIdx.x * 256 + threadIdx.x;
  if (e < N_EDGES) {
    int d = dst[e];
    int p = atomicAdd(&cnt[d], 1);
    ssrc[off[d] + p] = src[e];
  }
}

// ---------------- per-(node,head) softmax weights, lane-parallel over edges ----
// wgt[e*H + h] = exp(lrelu(el[src]+er[dst]) - m) / sum
template<int H>
__global__ void attw_k(const float* __restrict__ el, const float* __restrict__ er,
                       const int* __restrict__ off, const int* __restrict__ ssrc,
                       float* __restrict__ wgt) {
  int wid = (blockIdx.x * 256 + threadIdx.x) >> 6;  // global wave id
  int lane = threadIdx.x & 63;
  int n = wid / H, h = wid % H;  // H is 1 or 4 -> shifts
  if (n >= N_NODES) return;
  int s0 = off[n], s1 = off[n + 1];
  if (s0 == s1) return;
  float erv = er[n * H + h];
  float m = -INFINITY;
  for (int i = s0 + lane; i < s1; i += 64) {
    int s = ssrc[i];
    float x = el[s * H + h] + erv;
    x = (x > 0.f) ? x : 0.01f * x;
    m = fmaxf(m, x);
  }
  #pragma unroll
  for (int o = 32; o; o >>= 1) m = fmaxf(m, __shfl_xor(m, o));
  float ssum = 0.f;
  for (int i = s0 + lane; i < s1; i += 64) {
    int s = ssrc[i];
    float x = el[s * H + h] + erv;
    x = (x > 0.f) ? x : 0.01f * x;
    float ex = __expf(x - m);
    wgt[i * H + h] = ex;
    ssum += ex;
  }
  #pragma unroll
  for (int o = 32; o; o >>= 1) ssum += __shfl_xor(ssum, o);
  float rs = 1.f / ssum;
  for (int i = s0 + lane; i < s1; i += 64) wgt[i * H + h] *= rs;
}

// ---------------- layer-1 aggregation: 1 wave per node, all 4 heads ----------
// lane covers channels [lane*4, lane*4+4); head = lane>>4. Gathers full 1KB row.
__global__ __launch_bounds__(256) void agg4_k(const float* __restrict__ ft,
                                              const float* __restrict__ wgt,
                                              const int* __restrict__ off,
                                              const int* __restrict__ ssrc,
                                              const float* __restrict__ bias,
                                              float* __restrict__ out) {
  int wid = (blockIdx.x * 256 + threadIdx.x) >> 6;  // = node
  int lane = threadIdx.x & 63;
  if (wid >= N_NODES) return;
  int s0 = off[wid], s1 = off[wid + 1];
  const float4* ft4 = (const float4*)ft;
  int head = lane >> 4;
  float4 acc = make_float4(0.f, 0.f, 0.f, 0.f);
  #pragma unroll 4
  for (int i = s0; i < s1; ++i) {
    int s = ssrc[i];
    float w = wgt[i * 4 + head];
    float4 f = ft4[(size_t)s * 64 + lane];
    acc.x = fmaf(w, f.x, acc.x);
    acc.y = fmaf(w, f.y, acc.y);
    acc.z = fmaf(w, f.z, acc.z);
    acc.w = fmaf(w, f.w, acc.w);
  }
  float4 b4 = ((const float4*)bias)[lane];
  acc.x += b4.x; acc.y += b4.y; acc.z += b4.z; acc.w += b4.w;
  acc.x = (acc.x > 0.f) ? acc.x : expm1f(acc.x);
  acc.y = (acc.y > 0.f) ? acc.y : expm1f(acc.y);
  acc.z = (acc.z > 0.f) ? acc.z : expm1f(acc.z);
  acc.w = (acc.w > 0.f) ? acc.w : expm1f(acc.w);
  ((float4*)out)[(size_t)wid * 64 + lane] = acc;
}

// ---------------- layer-2 aggregation: 1 wave per node, 4 edges/iter ---------
// 16-lane group g handles edge i+g; lane&15 covers channels [(lane&15)*4, +4)
__global__ __launch_bounds__(256) void agg1_k(const float* __restrict__ ft,
                                              const float* __restrict__ wgt,
                                              const int* __restrict__ off,
                                              const int* __restrict__ ssrc,
                                              const float* __restrict__ bias,
                                              float* __restrict__ out) {
  int wid = (blockIdx.x * 256 + threadIdx.x) >> 6;  // = node
  int lane = threadIdx.x & 63;
  if (wid >= N_NODES) return;
  int s0 = off[wid], s1 = off[wid + 1];
  const float4* ft4 = (const float4*)ft;
  int g = lane >> 4, c = lane & 15;
  float4 acc = make_float4(0.f, 0.f, 0.f, 0.f);
  for (int i = s0 + g; i < s1; i += 4) {
    int s = ssrc[i];
    float w = wgt[i];
    float4 f = ft4[(size_t)s * 16 + c];
    acc.x = fmaf(w, f.x, acc.x);
    acc.y = fmaf(w, f.y, acc.y);
    acc.z = fmaf(w, f.z, acc.z);
    acc.w = fmaf(w, f.w, acc.w);
  }
  #pragma unroll
  for (int o = 16; o <= 32; o <<= 1) {
    acc.x += __shfl_xor(acc.x, o);
    acc.y += __shfl_xor(acc.y, o);
    acc.z += __shfl_xor(acc.z, o);
    acc.w += __shfl_xor(acc.w, o);
  }
  if (g == 0) {
    float4 b4 = ((const float4*)bias)[c];
    acc.x += b4.x; acc.y += b4.y; acc.z += b4.z; acc.w += b4.w;
    acc.x = (acc.x > 0.f) ? acc.x : expm1f(acc.x);
    acc.y = (acc.y > 0.f) ? acc.y : expm1f(acc.y);
    acc.z = (acc.z > 0.f) ? acc.z : expm1f(acc.z);
    acc.w = (acc.w > 0.f) ? acc.w : expm1f(acc.w);
    ((float4*)out)[(size_t)wid * 16 + c] = acc;
  }
}

extern "C" void kernel_launch(void* const* d_in, const int* in_sizes, int n_in,
                              void* d_out, int out_size, void* d_ws, size_t ws_size,
                              hipStream_t stream) {
  const float* x   = (const float*)d_in[0];
  const int*   src = (const int*)d_in[1];
  const int*   dst = (const int*)d_in[2];
  const float* W1  = (const float*)d_in[3];
  const float* al1 = (const float*)d_in[4];
  const float* ar1 = (const float*)d_in[5];
  const float* b1  = (const float*)d_in[6];
  const float* W2  = (const float*)d_in[7];
  const float* al2 = (const float*)d_in[8];
  const float* ar2 = (const float*)d_in[9];
  const float* b2  = (const float*)d_in[10];
  float* out = (float*)d_out;

  char* ws = (char*)d_ws;
  size_t wo = 0;
  auto alloc = [&](size_t b) { void* p = ws + wo; wo = (wo + b + 255) & ~(size_t)255; return p; };
  float* ft1 = (float*)alloc((size_t)N_NODES * 256 * 4);
  float* h1  = (float*)alloc((size_t)N_NODES * 256 * 4);
  float* el1 = (float*)alloc((size_t)N_NODES * 4 * 4);
  float* er1 = (float*)alloc((size_t)N_NODES * 4 * 4);
  int*   off = (int*)alloc((size_t)(N_NODES + 1) * 4);
  int*   cnt = (int*)alloc((size_t)N_NODES * 4);
  int*   bsum= (int*)alloc(256);
  int*   ssrc= (int*)alloc((size_t)N_EDGES * 4);
  float* wgt = (float*)alloc((size_t)N_EDGES * 4 * 4);
  float* ft2 = ft1;            // ft1 dead after agg1 -> reuse
  float* el2 = el1, *er2 = er1;

  // ---- CSR by dst (once; same graph both layers) ----
  hipMemsetAsync(cnt, 0, (size_t)N_NODES * 4, stream);
  hist_k<<<(N_EDGES + 255) / 256, 256, 0, stream>>>(dst, cnt);
  int nb = (N_NODES + 1023) / 1024;
  scan1_k<<<nb, 1024, 0, stream>>>(cnt, off, bsum);
  scan2_k<<<1, 64, 0, stream>>>(bsum, nb);
  scan3_k<<<nb, 1024, 0, stream>>>(off, bsum);
  hipMemsetAsync(cnt, 0, (size_t)N_NODES * 4, stream);
  place_k<<<(N_EDGES + 255) / 256, 256, 0, stream>>>(src, dst, off, cnt, ssrc);

  // ---- layer 1 (H=4, D=64) ----
  gemm64<IN_DIM, 256><<<dim3((N_NODES + 63) / 64, 4), 256, 0, stream>>>(x, W1, ft1, N_NODES);
  eler_k<256><<<N_NODES, 256, 0, stream>>>(ft1, al1, ar1, el1, er1);
  attw_k<4><<<(N_NODES * 4 + 3) / 4, 256, 0, stream>>>(el1, er1, off, ssrc, wgt);
  agg4_k<<<(N_NODES + 3) / 4, 256, 0, stream>>>(ft1, wgt, off, ssrc, b1, h1);

  // ---- layer 2 (H=1, D=64) ----
  gemm64<256, HID><<<dim3((N_NODES + 63) / 64, 1), 256, 0, stream>>>(h1, W2, ft2, N_NODES);
  eler_k<64><<<N_NODES, 64, 0, stream>>>(ft2, al2, ar2, el2, er2);
  attw_k<1><<<(N_NODES + 3) / 4, 256, 0, stream>>>(el2, er2, off, ssrc, wgt);
  agg1_k<<<(N_NODES + 3) / 4, 256, 0, stream>>>(ft2, wgt, off, ssrc, b2, out);
}

// Round 3
// 405.847 us; speedup vs baseline: 1.3864x; 1.1338x over previous
//
#include <hip/hip_runtime.h>
#include <hip/hip_bf16.h>
#include <math.h>

#define N_NODES 50000
#define N_EDGES 800000
#define IN_DIM 128
#define HID 64
#define HEADS 4

typedef unsigned short ushort_t;

static __device__ __forceinline__ ushort_t f2bf(float f) {
  __hip_bfloat16 b = __float2bfloat16(f);
  return *(ushort_t*)&b;
}
static __device__ __forceinline__ float bf2f(ushort_t u) {
  __hip_bfloat16 b = *(__hip_bfloat16*)&u;
  return __bfloat162float(b);
}

// ---------------- tiled fp32 GEMM: C[M,NC] = A[M,K] * B[K,NC], bf16 output ----
template<int K, int NC>
__global__ __launch_bounds__(256) void gemm64(const float* __restrict__ A,
                                              const float* __restrict__ B,
                                              __hip_bfloat16* __restrict__ Cb, int M) {
  constexpr int BK = 32;
  __shared__ float As[BK][65];
  __shared__ float Bs[BK][64];
  const int tid = threadIdx.x;
  const int m0 = blockIdx.x * 64;
  const int n0 = blockIdx.y * 64;
  const int ty = tid >> 4, tx = tid & 15;
  float acc[4][4] = {};
  const int arow = tid >> 3;
  const int akc  = (tid & 7) * 4;
  const int bkr  = tid >> 4;
  const int bc   = (tid & 15) * 4;

  for (int k0 = 0; k0 < K; k0 += BK) {
    #pragma unroll
    for (int j = 0; j < 2; ++j) {
      int r = arow + j * 32;
      float4 a = make_float4(0.f, 0.f, 0.f, 0.f);
      if (m0 + r < M) a = *(const float4*)&A[(size_t)(m0 + r) * K + k0 + akc];
      As[akc + 0][r] = a.x; As[akc + 1][r] = a.y;
      As[akc + 2][r] = a.z; As[akc + 3][r] = a.w;
    }
    #pragma unroll
    for (int j = 0; j < 2; ++j) {
      int kr = bkr + j * 16;
      *(float4*)&Bs[kr][bc] = *(const float4*)&B[(size_t)(k0 + kr) * NC + n0 + bc];
    }
    __syncthreads();
    #pragma unroll
    for (int k = 0; k < BK; ++k) {
      float a_[4], b_[4];
      #pragma unroll
      for (int i = 0; i < 4; ++i) a_[i] = As[k][ty * 4 + i];
      float4 b4 = *(const float4*)&Bs[k][tx * 4];
      b_[0] = b4.x; b_[1] = b4.y; b_[2] = b4.z; b_[3] = b4.w;
      #pragma unroll
      for (int i = 0; i < 4; ++i)
        #pragma unroll
        for (int j = 0; j < 4; ++j)
          acc[i][j] = fmaf(a_[i], b_[j], acc[i][j]);
    }
    __syncthreads();
  }
  #pragma unroll
  for (int i = 0; i < 4; ++i) {
    int r = m0 + ty * 4 + i;
    if (r < M) {
      ushort4 u;
      u.x = f2bf(acc[i][0]); u.y = f2bf(acc[i][1]);
      u.z = f2bf(acc[i][2]); u.w = f2bf(acc[i][3]);
      *(ushort4*)&Cb[(size_t)r * NC + n0 + tx * 4] = u;
    }
  }
}

// ---------------- el/er: per-node attention dot products (bf16 ft) -----------
template<int HD>
__global__ void eler_k(const __hip_bfloat16* __restrict__ ft, const float* __restrict__ al,
                       const float* __restrict__ ar, float* __restrict__ el,
                       float* __restrict__ er) {
  int n = blockIdx.x;
  int t = threadIdx.x;
  float f = __bfloat162float(ft[(size_t)n * HD + t]);
  float vl = f * al[t], vr = f * ar[t];
  #pragma unroll
  for (int s = 32; s; s >>= 1) { vl += __shfl_down(vl, s); vr += __shfl_down(vr, s); }
  if ((t & 63) == 0) {
    int h = t >> 6;
    el[n * (HD / 64) + h] = vl;
    er[n * (HD / 64) + h] = vr;
  }
}

// ---------------- CSR build (histogram + scan + place) ----------------
__global__ void hist_k(const int* __restrict__ dst, int* __restrict__ cnt) {
  int e = blockIdx.x * 256 + threadIdx.x;
  if (e < N_EDGES) atomicAdd(&cnt[dst[e]], 1);
}

__global__ void scan1_k(const int* __restrict__ cnt, int* __restrict__ off,
                        int* __restrict__ bsum) {
  __shared__ int lds[1024];
  int tid = threadIdx.x;
  int i = blockIdx.x * 1024 + tid;
  int v = (i < N_NODES) ? cnt[i] : 0;
  lds[tid] = v;
  __syncthreads();
  for (int s = 1; s < 1024; s <<= 1) {
    int t = (tid >= s) ? lds[tid - s] : 0;
    __syncthreads();
    lds[tid] += t;
    __syncthreads();
  }
  if (i < N_NODES) off[i] = lds[tid] - v;
  if (tid == 1023) bsum[blockIdx.x] = lds[1023];
}

__global__ void scan2_k(int* __restrict__ bsum, int nb) {
  int lane = threadIdx.x;
  int v = (lane < nb) ? bsum[lane] : 0;
  int orig = v;
  for (int s = 1; s < 64; s <<= 1) { int t = __shfl_up(v, s); if (lane >= s) v += t; }
  if (lane < nb) bsum[lane] = v - orig;
}

__global__ void scan3_k(int* __restrict__ off, const int* __restrict__ bsum) {
  int i = blockIdx.x * 1024 + threadIdx.x;
  if (i < N_NODES) off[i] += bsum[blockIdx.x];
  if (i == 0) off[N_NODES] = N_EDGES;
}

__global__ void place_k(const int* __restrict__ src, const int* __restrict__ dst,
                        const int* __restrict__ off, int* __restrict__ cnt,
                        int* __restrict__ ssrc) {
  int e = blockIdx.x * 256 + threadIdx.x;
  if (e < N_EDGES) {
    int d = dst[e];
    int p = atomicAdd(&cnt[d], 1);
    ssrc[off[d] + p] = src[e];
  }
}

// ---------------- per-(node,head) softmax weights ----------------
template<int H>
__global__ void attw_k(const float* __restrict__ el, const float* __restrict__ er,
                       const int* __restrict__ off, const int* __restrict__ ssrc,
                       float* __restrict__ wgt) {
  int wid = (blockIdx.x * 256 + threadIdx.x) >> 6;
  int lane = threadIdx.x & 63;
  int n = wid / H, h = wid % H;
  if (n >= N_NODES) return;
  int s0 = off[n], s1 = off[n + 1];
  if (s0 == s1) return;
  float erv = er[n * H + h];
  float m = -INFINITY;
  for (int i = s0 + lane; i < s1; i += 64) {
    int s = ssrc[i];
    float x = el[s * H + h] + erv;
    x = (x > 0.f) ? x : 0.01f * x;
    m = fmaxf(m, x);
  }
  #pragma unroll
  for (int o = 32; o; o >>= 1) m = fmaxf(m, __shfl_xor(m, o));
  float ssum = 0.f;
  for (int i = s0 + lane; i < s1; i += 64) {
    int s = ssrc[i];
    float x = el[s * H + h] + erv;
    x = (x > 0.f) ? x : 0.01f * x;
    float ex = __expf(x - m);
    wgt[i * H + h] = ex;
    ssum += ex;
  }
  #pragma unroll
  for (int o = 32; o; o >>= 1) ssum += __shfl_xor(ssum, o);
  float rs = 1.f / ssum;
  for (int i = s0 + lane; i < s1; i += 64) wgt[i * H + h] *= rs;
}

// ---------------- layer-1 aggregation: bf16 ft, 2 edges per wave -------------
// half = lane>>5 handles edge i+half; sl = lane&31 covers channels [sl*8, sl*8+8)
__global__ __launch_bounds__(256) void agg4_k(const __hip_bfloat16* __restrict__ ftb,
                                              const float* __restrict__ wgt,
                                              const int* __restrict__ off,
                                              const int* __restrict__ ssrc,
                                              const float* __restrict__ bias,
                                              float* __restrict__ out) {
  int n = (blockIdx.x * 256 + threadIdx.x) >> 6;
  int lane = threadIdx.x & 63;
  if (n >= N_NODES) return;
  int s0 = off[n], s1 = off[n + 1];
  int half = lane >> 5, sl = lane & 31;
  int head = sl >> 3;
  const ushort4* ft8 = (const ushort4*)ftb;  // two ushort4 = 8 bf16 per lane
  float acc[8] = {};
  #pragma unroll 4
  for (int i = s0; i < s1; i += 2) {
    int e = i + half;
    if (e < s1) {
      int s = ssrc[e];
      float w = wgt[e * 4 + head];
      // 16B load: 8 bf16 channels at [s*256 + sl*8]
      ushort4 u0 = ft8[((size_t)s * 256 + sl * 8) >> 2];
      ushort4 u1 = ft8[(((size_t)s * 256 + sl * 8) >> 2) + 1];
      acc[0] = fmaf(w, bf2f(u0.x), acc[0]);
      acc[1] = fmaf(w, bf2f(u0.y), acc[1]);
      acc[2] = fmaf(w, bf2f(u0.z), acc[2]);
      acc[3] = fmaf(w, bf2f(u0.w), acc[3]);
      acc[4] = fmaf(w, bf2f(u1.x), acc[4]);
      acc[5] = fmaf(w, bf2f(u1.y), acc[5]);
      acc[6] = fmaf(w, bf2f(u1.z), acc[6]);
      acc[7] = fmaf(w, bf2f(u1.w), acc[7]);
    }
  }
  #pragma unroll
  for (int j = 0; j < 8; ++j) acc[j] += __shfl_xor(acc[j], 32);
  if (half == 0) {
    float4 b0 = ((const float4*)bias)[sl * 2];
    float4 b1 = ((const float4*)bias)[sl * 2 + 1];
    float o[8] = {acc[0] + b0.x, acc[1] + b0.y, acc[2] + b0.z, acc[3] + b0.w,
                  acc[4] + b1.x, acc[5] + b1.y, acc[6] + b1.z, acc[7] + b1.w};
    #pragma unroll
    for (int j = 0; j < 8; ++j) o[j] = (o[j] > 0.f) ? o[j] : expm1f(o[j]);
    float4* out4 = (float4*)out;
    out4[(size_t)n * 64 + sl * 2]     = make_float4(o[0], o[1], o[2], o[3]);
    out4[(size_t)n * 64 + sl * 2 + 1] = make_float4(o[4], o[5], o[6], o[7]);
  }
}

// ---------------- layer-2 aggregation: bf16 ft, 8 edges per iteration --------
// g = lane>>3 handles edge i+g; c = lane&7 covers channels [c*8, c*8+8)
__global__ __launch_bounds__(256) void agg1_k(const __hip_bfloat16* __restrict__ ftb,
                                              const float* __restrict__ wgt,
                                              const int* __restrict__ off,
                                              const int* __restrict__ ssrc,
                                              const float* __restrict__ bias,
                                              float* __restrict__ out) {
  int n = (blockIdx.x * 256 + threadIdx.x) >> 6;
  int lane = threadIdx.x & 63;
  if (n >= N_NODES) return;
  int s0 = off[n], s1 = off[n + 1];
  int g = lane >> 3, c = lane & 7;
  const ushort4* ft8 = (const ushort4*)ftb;
  float acc[8] = {};
  #pragma unroll 2
  for (int i = s0; i < s1; i += 8) {
    int e = i + g;
    if (e < s1) {
      int s = ssrc[e];
      float w = wgt[e];
      ushort4 u0 = ft8[((size_t)s * 64 + c * 8) >> 2];
      ushort4 u1 = ft8[(((size_t)s * 64 + c * 8) >> 2) + 1];
      acc[0] = fmaf(w, bf2f(u0.x), acc[0]);
      acc[1] = fmaf(w, bf2f(u0.y), acc[1]);
      acc[2] = fmaf(w, bf2f(u0.z), acc[2]);
      acc[3] = fmaf(w, bf2f(u0.w), acc[3]);
      acc[4] = fmaf(w, bf2f(u1.x), acc[4]);
      acc[5] = fmaf(w, bf2f(u1.y), acc[5]);
      acc[6] = fmaf(w, bf2f(u1.z), acc[6]);
      acc[7] = fmaf(w, bf2f(u1.w), acc[7]);
    }
  }
  #pragma unroll
  for (int o = 8; o <= 32; o <<= 1)
    #pragma unroll
    for (int j = 0; j < 8; ++j) acc[j] += __shfl_xor(acc[j], o);
  if (g == 0) {
    float4 b0 = ((const float4*)bias)[c * 2];
    float4 b1 = ((const float4*)bias)[c * 2 + 1];
    float o[8] = {acc[0] + b0.x, acc[1] + b0.y, acc[2] + b0.z, acc[3] + b0.w,
                  acc[4] + b1.x, acc[5] + b1.y, acc[6] + b1.z, acc[7] + b1.w};
    #pragma unroll
    for (int j = 0; j < 8; ++j) o[j] = (o[j] > 0.f) ? o[j] : expm1f(o[j]);
    float4* out4 = (float4*)out;
    out4[(size_t)n * 16 + c * 2]     = make_float4(o[0], o[1], o[2], o[3]);
    out4[(size_t)n * 16 + c * 2 + 1] = make_float4(o[4], o[5], o[6], o[7]);
  }
}

extern "C" void kernel_launch(void* const* d_in, const int* in_sizes, int n_in,
                              void* d_out, int out_size, void* d_ws, size_t ws_size,
                              hipStream_t stream) {
  const float* x   = (const float*)d_in[0];
  const int*   src = (const int*)d_in[1];
  const int*   dst = (const int*)d_in[2];
  const float* W1  = (const float*)d_in[3];
  const float* al1 = (const float*)d_in[4];
  const float* ar1 = (const float*)d_in[5];
  const float* b1  = (const float*)d_in[6];
  const float* W2  = (const float*)d_in[7];
  const float* al2 = (const float*)d_in[8];
  const float* ar2 = (const float*)d_in[9];
  const float* b2  = (const float*)d_in[10];
  float* out = (float*)d_out;

  char* ws = (char*)d_ws;
  size_t wo = 0;
  auto alloc = [&](size_t b) { void* p = ws + wo; wo = (wo + b + 255) & ~(size_t)255; return p; };
  __hip_bfloat16* ft1b = (__hip_bfloat16*)alloc((size_t)N_NODES * 256 * 2);
  float* h1  = (float*)alloc((size_t)N_NODES * 256 * 4);
  float* el1 = (float*)alloc((size_t)N_NODES * 4 * 4);
  float* er1 = (float*)alloc((size_t)N_NODES * 4 * 4);
  int*   off = (int*)alloc((size_t)(N_NODES + 1) * 4);
  int*   cnt = (int*)alloc((size_t)N_NODES * 4);
  int*   bsum= (int*)alloc(256);
  int*   ssrc= (int*)alloc((size_t)N_EDGES * 4);
  float* wgt = (float*)alloc((size_t)N_EDGES * 4 * 4);
  __hip_bfloat16* ft2b = ft1b;   // ft1b dead after agg4 -> reuse
  float* el2 = el1, *er2 = er1;

  // ---- CSR by dst (once; same graph both layers) ----
  hipMemsetAsync(cnt, 0, (size_t)N_NODES * 4, stream);
  hist_k<<<(N_EDGES + 255) / 256, 256, 0, stream>>>(dst, cnt);
  int nb = (N_NODES + 1023) / 1024;
  scan1_k<<<nb, 1024, 0, stream>>>(cnt, off, bsum);
  scan2_k<<<1, 64, 0, stream>>>(bsum, nb);
  scan3_k<<<nb, 1024, 0, stream>>>(off, bsum);
  hipMemsetAsync(cnt, 0, (size_t)N_NODES * 4, stream);
  place_k<<<(N_EDGES + 255) / 256, 256, 0, stream>>>(src, dst, off, cnt, ssrc);

  // ---- layer 1 (H=4, D=64) ----
  gemm64<IN_DIM, 256><<<dim3((N_NODES + 63) / 64, 4), 256, 0, stream>>>(x, W1, ft1b, N_NODES);
  eler_k<256><<<N_NODES, 256, 0, stream>>>(ft1b, al1, ar1, el1, er1);
  attw_k<4><<<(N_NODES * 4 + 3) / 4, 256, 0, stream>>>(el1, er1, off, ssrc, wgt);
  agg4_k<<<(N_NODES + 3) / 4, 256, 0, stream>>>(ft1b, wgt, off, ssrc, b1, h1);

  // ---- layer 2 (H=1, D=64) ----
  gemm64<256, HID><<<dim3((N_NODES + 63) / 64, 1), 256, 0, stream>>>(h1, W2, ft2b, N_NODES);
  eler_k<64><<<N_NODES, 64, 0, stream>>>(ft2b, al2, ar2, el2, er2);
  attw_k<1><<<(N_NODES + 3) / 4, 256, 0, stream>>>(el2, er2, off, ssrc, wgt);
  agg1_k<<<(N_NODES + 3) / 4, 256, 0, stream>>>(ft2b, wgt, off, ssrc, b2, out);
}

// Round 4
// 354.080 us; speedup vs baseline: 1.5891x; 1.1462x over previous
//
#include <hip/hip_runtime.h>
#include <hip/hip_bf16.h>
#include <math.h>

#define N_NODES 50000
#define N_EDGES 800000
#define IN_DIM 128
#define HID 64
#define HEADS 4

typedef unsigned short ushort_t;

static __device__ __forceinline__ ushort_t f2bf(float f) {
  __hip_bfloat16 b = __float2bfloat16(f);
  return *(ushort_t*)&b;
}
static __device__ __forceinline__ float bf2f(ushort_t u) {
  __hip_bfloat16 b = *(__hip_bfloat16*)&u;
  return __bfloat162float(b);
}
static __device__ __forceinline__ float lrelu(float x) {
  return (x > 0.f) ? x : 0.01f * x;
}

// ---------------- tiled fp32 GEMM: C[M,NC] = A[M,K] * B[K,NC], bf16 output ----
template<int K, int NC>
__global__ __launch_bounds__(256) void gemm64(const float* __restrict__ A,
                                              const float* __restrict__ B,
                                              __hip_bfloat16* __restrict__ Cb, int M) {
  constexpr int BK = 32;
  __shared__ float As[BK][65];
  __shared__ float Bs[BK][64];
  const int tid = threadIdx.x;
  const int m0 = blockIdx.x * 64;
  const int n0 = blockIdx.y * 64;
  const int ty = tid >> 4, tx = tid & 15;
  float acc[4][4] = {};
  const int arow = tid >> 3;
  const int akc  = (tid & 7) * 4;
  const int bkr  = tid >> 4;
  const int bc   = (tid & 15) * 4;

  for (int k0 = 0; k0 < K; k0 += BK) {
    #pragma unroll
    for (int j = 0; j < 2; ++j) {
      int r = arow + j * 32;
      float4 a = make_float4(0.f, 0.f, 0.f, 0.f);
      if (m0 + r < M) a = *(const float4*)&A[(size_t)(m0 + r) * K + k0 + akc];
      As[akc + 0][r] = a.x; As[akc + 1][r] = a.y;
      As[akc + 2][r] = a.z; As[akc + 3][r] = a.w;
    }
    #pragma unroll
    for (int j = 0; j < 2; ++j) {
      int kr = bkr + j * 16;
      *(float4*)&Bs[kr][bc] = *(const float4*)&B[(size_t)(k0 + kr) * NC + n0 + bc];
    }
    __syncthreads();
    #pragma unroll
    for (int k = 0; k < BK; ++k) {
      float a_[4], b_[4];
      #pragma unroll
      for (int i = 0; i < 4; ++i) a_[i] = As[k][ty * 4 + i];
      float4 b4 = *(const float4*)&Bs[k][tx * 4];
      b_[0] = b4.x; b_[1] = b4.y; b_[2] = b4.z; b_[3] = b4.w;
      #pragma unroll
      for (int i = 0; i < 4; ++i)
        #pragma unroll
        for (int j = 0; j < 4; ++j)
          acc[i][j] = fmaf(a_[i], b_[j], acc[i][j]);
    }
    __syncthreads();
  }
  #pragma unroll
  for (int i = 0; i < 4; ++i) {
    int r = m0 + ty * 4 + i;
    if (r < M) {
      ushort4 u;
      u.x = f2bf(acc[i][0]); u.y = f2bf(acc[i][1]);
      u.z = f2bf(acc[i][2]); u.w = f2bf(acc[i][3]);
      *(ushort4*)&Cb[(size_t)r * NC + n0 + tx * 4] = u;
    }
  }
}

// ---------------- el/er: per-node attention dot products (bf16 ft) -----------
template<int HD>
__global__ void eler_k(const __hip_bfloat16* __restrict__ ft, const float* __restrict__ al,
                       const float* __restrict__ ar, float* __restrict__ el,
                       float* __restrict__ er) {
  int n = blockIdx.x;
  int t = threadIdx.x;
  float f = __bfloat162float(ft[(size_t)n * HD + t]);
  float vl = f * al[t], vr = f * ar[t];
  #pragma unroll
  for (int s = 32; s; s >>= 1) { vl += __shfl_down(vl, s); vr += __shfl_down(vr, s); }
  if ((t & 63) == 0) {
    int h = t >> 6;
    el[n * (HD / 64) + h] = vl;
    er[n * (HD / 64) + h] = vr;
  }
}

// ---------------- CSR build (histogram + scan + place) ----------------
__global__ void hist_k(const int* __restrict__ dst, int* __restrict__ cnt) {
  int e = blockIdx.x * 256 + threadIdx.x;
  if (e < N_EDGES) atomicAdd(&cnt[dst[e]], 1);
}

__global__ void scan1_k(const int* __restrict__ cnt, int* __restrict__ off,
                        int* __restrict__ bsum) {
  __shared__ int lds[1024];
  int tid = threadIdx.x;
  int i = blockIdx.x * 1024 + tid;
  int v = (i < N_NODES) ? cnt[i] : 0;
  lds[tid] = v;
  __syncthreads();
  for (int s = 1; s < 1024; s <<= 1) {
    int t = (tid >= s) ? lds[tid - s] : 0;
    __syncthreads();
    lds[tid] += t;
    __syncthreads();
  }
  if (i < N_NODES) off[i] = lds[tid] - v;
  if (tid == 1023) bsum[blockIdx.x] = lds[1023];
}

__global__ void scan2_k(int* __restrict__ bsum, int nb) {
  int lane = threadIdx.x;
  int v = (lane < nb) ? bsum[lane] : 0;
  int orig = v;
  for (int s = 1; s < 64; s <<= 1) { int t = __shfl_up(v, s); if (lane >= s) v += t; }
  if (lane < nb) bsum[lane] = v - orig;
}

__global__ void scan3_k(int* __restrict__ off, const int* __restrict__ bsum) {
  int i = blockIdx.x * 1024 + threadIdx.x;
  if (i < N_NODES) off[i] += bsum[blockIdx.x];
  if (i == 0) off[N_NODES] = N_EDGES;
}

__global__ void place_k(const int* __restrict__ src, const int* __restrict__ dst,
                        const int* __restrict__ off, int* __restrict__ cnt,
                        int* __restrict__ ssrc) {
  int e = blockIdx.x * 256 + threadIdx.x;
  if (e < N_EDGES) {
    int d = dst[e];
    int p = atomicAdd(&cnt[d], 1);
    ssrc[off[d] + p] = src[e];
  }
}

// ---- attention weights, H=4: one wave per node, all heads; single gather pass
// wgt[e] = float4 of exp(x - m) (unnormalized); rs[n] = float4 of 1/sum
__global__ __launch_bounds__(256) void attw4_k(const float* __restrict__ el,
                                               const float* __restrict__ er,
                                               const int* __restrict__ off,
                                               const int* __restrict__ ssrc,
                                               float* __restrict__ wgt,
                                               float* __restrict__ rs) {
  int n = (blockIdx.x * 256 + threadIdx.x) >> 6;
  int lane = threadIdx.x & 63;
  if (n >= N_NODES) return;
  int s0 = off[n], s1 = off[n + 1];
  if (s0 >= s1) {
    if (lane == 0) ((float4*)rs)[n] = make_float4(0.f, 0.f, 0.f, 0.f);
    return;
  }
  const float4* el4 = (const float4*)el;
  float4 erv = ((const float4*)er)[n];
  float4 m = make_float4(-INFINITY, -INFINITY, -INFINITY, -INFINITY);
  float4 x0 = m;
  int i0 = s0 + lane;
  bool v0 = (i0 < s1);
  if (v0) {
    int s = ssrc[i0];
    float4 e = el4[s];
    x0.x = lrelu(e.x + erv.x); x0.y = lrelu(e.y + erv.y);
    x0.z = lrelu(e.z + erv.z); x0.w = lrelu(e.w + erv.w);
    m = x0;
  }
  for (int i = i0 + 64; i < s1; i += 64) {   // degree > 64: essentially never
    int s = ssrc[i];
    float4 e = el4[s];
    m.x = fmaxf(m.x, lrelu(e.x + erv.x)); m.y = fmaxf(m.y, lrelu(e.y + erv.y));
    m.z = fmaxf(m.z, lrelu(e.z + erv.z)); m.w = fmaxf(m.w, lrelu(e.w + erv.w));
  }
  #pragma unroll
  for (int o = 32; o; o >>= 1) {
    m.x = fmaxf(m.x, __shfl_xor(m.x, o)); m.y = fmaxf(m.y, __shfl_xor(m.y, o));
    m.z = fmaxf(m.z, __shfl_xor(m.z, o)); m.w = fmaxf(m.w, __shfl_xor(m.w, o));
  }
  float4 sum = make_float4(0.f, 0.f, 0.f, 0.f);
  if (v0) {
    float4 ex;
    ex.x = __expf(x0.x - m.x); ex.y = __expf(x0.y - m.y);
    ex.z = __expf(x0.z - m.z); ex.w = __expf(x0.w - m.w);
    sum = ex;
    ((float4*)wgt)[i0] = ex;
  }
  for (int i = i0 + 64; i < s1; i += 64) {
    int s = ssrc[i];
    float4 e = el4[s];
    float4 ex;
    ex.x = __expf(lrelu(e.x + erv.x) - m.x); ex.y = __expf(lrelu(e.y + erv.y) - m.y);
    ex.z = __expf(lrelu(e.z + erv.z) - m.z); ex.w = __expf(lrelu(e.w + erv.w) - m.w);
    sum.x += ex.x; sum.y += ex.y; sum.z += ex.z; sum.w += ex.w;
    ((float4*)wgt)[i] = ex;
  }
  #pragma unroll
  for (int o = 32; o; o >>= 1) {
    sum.x += __shfl_xor(sum.x, o); sum.y += __shfl_xor(sum.y, o);
    sum.z += __shfl_xor(sum.z, o); sum.w += __shfl_xor(sum.w, o);
  }
  if (lane == 0)
    ((float4*)rs)[n] = make_float4(1.f / sum.x, 1.f / sum.y, 1.f / sum.z, 1.f / sum.w);
}

// ---- attention weights, H=1 ----
__global__ __launch_bounds__(256) void attw1_k(const float* __restrict__ el,
                                               const float* __restrict__ er,
                                               const int* __restrict__ off,
                                               const int* __restrict__ ssrc,
                                               float* __restrict__ wgt,
                                               float* __restrict__ rs) {
  int n = (blockIdx.x * 256 + threadIdx.x) >> 6;
  int lane = threadIdx.x & 63;
  if (n >= N_NODES) return;
  int s0 = off[n], s1 = off[n + 1];
  if (s0 >= s1) {
    if (lane == 0) rs[n] = 0.f;
    return;
  }
  float erv = er[n];
  float m = -INFINITY, x0 = -INFINITY;
  int i0 = s0 + lane;
  bool v0 = (i0 < s1);
  if (v0) { x0 = lrelu(el[ssrc[i0]] + erv); m = x0; }
  for (int i = i0 + 64; i < s1; i += 64) m = fmaxf(m, lrelu(el[ssrc[i]] + erv));
  #pragma unroll
  for (int o = 32; o; o >>= 1) m = fmaxf(m, __shfl_xor(m, o));
  float sum = 0.f;
  if (v0) { float ex = __expf(x0 - m); sum = ex; wgt[i0] = ex; }
  for (int i = i0 + 64; i < s1; i += 64) {
    float ex = __expf(lrelu(el[ssrc[i]] + erv) - m);
    sum += ex;
    wgt[i] = ex;
  }
  #pragma unroll
  for (int o = 32; o; o >>= 1) sum += __shfl_xor(sum, o);
  if (lane == 0) rs[n] = 1.f / sum;
}

// ---------------- layer-1 aggregation: bf16 ft, 2 edges per wave -------------
__global__ __launch_bounds__(256) void agg4_k(const __hip_bfloat16* __restrict__ ftb,
                                              const float* __restrict__ wgt,
                                              const float* __restrict__ rs,
                                              const int* __restrict__ off,
                                              const int* __restrict__ ssrc,
                                              const float* __restrict__ bias,
                                              float* __restrict__ out) {
  int n = (blockIdx.x * 256 + threadIdx.x) >> 6;
  int lane = threadIdx.x & 63;
  if (n >= N_NODES) return;
  int s0 = off[n], s1 = off[n + 1];
  int half = lane >> 5, sl = lane & 31;
  int head = sl >> 3;
  const ushort4* ft8 = (const ushort4*)ftb;
  float acc[8] = {};
  #pragma unroll 4
  for (int i = s0; i < s1; i += 2) {
    int e = i + half;
    if (e < s1) {
      int s = ssrc[e];
      float w = wgt[e * 4 + head];
      ushort4 u0 = ft8[((size_t)s * 256 + sl * 8) >> 2];
      ushort4 u1 = ft8[(((size_t)s * 256 + sl * 8) >> 2) + 1];
      acc[0] = fmaf(w, bf2f(u0.x), acc[0]);
      acc[1] = fmaf(w, bf2f(u0.y), acc[1]);
      acc[2] = fmaf(w, bf2f(u0.z), acc[2]);
      acc[3] = fmaf(w, bf2f(u0.w), acc[3]);
      acc[4] = fmaf(w, bf2f(u1.x), acc[4]);
      acc[5] = fmaf(w, bf2f(u1.y), acc[5]);
      acc[6] = fmaf(w, bf2f(u1.z), acc[6]);
      acc[7] = fmaf(w, bf2f(u1.w), acc[7]);
    }
  }
  #pragma unroll
  for (int j = 0; j < 8; ++j) acc[j] += __shfl_xor(acc[j], 32);
  if (half == 0) {
    float rsv = rs[n * 4 + head];
    float4 b0 = ((const float4*)bias)[sl * 2];
    float4 b1 = ((const float4*)bias)[sl * 2 + 1];
    float o[8] = {fmaf(acc[0], rsv, b0.x), fmaf(acc[1], rsv, b0.y),
                  fmaf(acc[2], rsv, b0.z), fmaf(acc[3], rsv, b0.w),
                  fmaf(acc[4], rsv, b1.x), fmaf(acc[5], rsv, b1.y),
                  fmaf(acc[6], rsv, b1.z), fmaf(acc[7], rsv, b1.w)};
    #pragma unroll
    for (int j = 0; j < 8; ++j) o[j] = (o[j] > 0.f) ? o[j] : expm1f(o[j]);
    float4* out4 = (float4*)out;
    out4[(size_t)n * 64 + sl * 2]     = make_float4(o[0], o[1], o[2], o[3]);
    out4[(size_t)n * 64 + sl * 2 + 1] = make_float4(o[4], o[5], o[6], o[7]);
  }
}

// ---------------- layer-2 aggregation: bf16 ft, 8 edges per iteration --------
__global__ __launch_bounds__(256) void agg1_k(const __hip_bfloat16* __restrict__ ftb,
                                              const float* __restrict__ wgt,
                                              const float* __restrict__ rs,
                                              const int* __restrict__ off,
                                              const int* __restrict__ ssrc,
                                              const float* __restrict__ bias,
                                              float* __restrict__ out) {
  int n = (blockIdx.x * 256 + threadIdx.x) >> 6;
  int lane = threadIdx.x & 63;
  if (n >= N_NODES) return;
  int s0 = off[n], s1 = off[n + 1];
  int g = lane >> 3, c = lane & 7;
  const ushort4* ft8 = (const ushort4*)ftb;
  float acc[8] = {};
  #pragma unroll 2
  for (int i = s0; i < s1; i += 8) {
    int e = i + g;
    if (e < s1) {
      int s = ssrc[e];
      float w = wgt[e];
      ushort4 u0 = ft8[((size_t)s * 64 + c * 8) >> 2];
      ushort4 u1 = ft8[(((size_t)s * 64 + c * 8) >> 2) + 1];
      acc[0] = fmaf(w, bf2f(u0.x), acc[0]);
      acc[1] = fmaf(w, bf2f(u0.y), acc[1]);
      acc[2] = fmaf(w, bf2f(u0.z), acc[2]);
      acc[3] = fmaf(w, bf2f(u0.w), acc[3]);
      acc[4] = fmaf(w, bf2f(u1.x), acc[4]);
      acc[5] = fmaf(w, bf2f(u1.y), acc[5]);
      acc[6] = fmaf(w, bf2f(u1.z), acc[6]);
      acc[7] = fmaf(w, bf2f(u1.w), acc[7]);
    }
  }
  #pragma unroll
  for (int o = 8; o <= 32; o <<= 1)
    #pragma unroll
    for (int j = 0; j < 8; ++j) acc[j] += __shfl_xor(acc[j], o);
  if (g == 0) {
    float rsv = rs[n];
    float4 b0 = ((const float4*)bias)[c * 2];
    float4 b1 = ((const float4*)bias)[c * 2 + 1];
    float o[8] = {fmaf(acc[0], rsv, b0.x), fmaf(acc[1], rsv, b0.y),
                  fmaf(acc[2], rsv, b0.z), fmaf(acc[3], rsv, b0.w),
                  fmaf(acc[4], rsv, b1.x), fmaf(acc[5], rsv, b1.y),
                  fmaf(acc[6], rsv, b1.z), fmaf(acc[7], rsv, b1.w)};
    #pragma unroll
    for (int j = 0; j < 8; ++j) o[j] = (o[j] > 0.f) ? o[j] : expm1f(o[j]);
    float4* out4 = (float4*)out;
    out4[(size_t)n * 16 + c * 2]     = make_float4(o[0], o[1], o[2], o[3]);
    out4[(size_t)n * 16 + c * 2 + 1] = make_float4(o[4], o[5], o[6], o[7]);
  }
}

extern "C" void kernel_launch(void* const* d_in, const int* in_sizes, int n_in,
                              void* d_out, int out_size, void* d_ws, size_t ws_size,
                              hipStream_t stream) {
  const float* x   = (const float*)d_in[0];
  const int*   src = (const int*)d_in[1];
  const int*   dst = (const int*)d_in[2];
  const float* W1  = (const float*)d_in[3];
  const float* al1 = (const float*)d_in[4];
  const float* ar1 = (const float*)d_in[5];
  const float* b1  = (const float*)d_in[6];
  const float* W2  = (const float*)d_in[7];
  const float* al2 = (const float*)d_in[8];
  const float* ar2 = (const float*)d_in[9];
  const float* b2  = (const float*)d_in[10];
  float* out = (float*)d_out;

  char* ws = (char*)d_ws;
  size_t wo = 0;
  auto alloc = [&](size_t b) { void* p = ws + wo; wo = (wo + b + 255) & ~(size_t)255; return p; };
  __hip_bfloat16* ft1b = (__hip_bfloat16*)alloc((size_t)N_NODES * 256 * 2);
  float* h1  = (float*)alloc((size_t)N_NODES * 256 * 4);
  float* el1 = (float*)alloc((size_t)N_NODES * 4 * 4);
  float* er1 = (float*)alloc((size_t)N_NODES * 4 * 4);
  float* rs  = (float*)alloc((size_t)N_NODES * 4 * 4);
  int*   off = (int*)alloc((size_t)(N_NODES + 1) * 4);
  int*   cnt = (int*)alloc((size_t)N_NODES * 4);
  int*   bsum= (int*)alloc(256);
  int*   ssrc= (int*)alloc((size_t)N_EDGES * 4);
  float* wgt = (float*)alloc((size_t)N_EDGES * 4 * 4);
  __hip_bfloat16* ft2b = ft1b;   // ft1b dead after agg4 -> reuse
  float* el2 = el1, *er2 = er1;

  // ---- CSR by dst (once; same graph both layers) ----
  hipMemsetAsync(cnt, 0, (size_t)N_NODES * 4, stream);
  hist_k<<<(N_EDGES + 255) / 256, 256, 0, stream>>>(dst, cnt);
  int nb = (N_NODES + 1023) / 1024;
  scan1_k<<<nb, 1024, 0, stream>>>(cnt, off, bsum);
  scan2_k<<<1, 64, 0, stream>>>(bsum, nb);
  scan3_k<<<nb, 1024, 0, stream>>>(off, bsum);
  hipMemsetAsync(cnt, 0, (size_t)N_NODES * 4, stream);
  place_k<<<(N_EDGES + 255) / 256, 256, 0, stream>>>(src, dst, off, cnt, ssrc);

  // ---- layer 1 (H=4, D=64) ----
  gemm64<IN_DIM, 256><<<dim3((N_NODES + 63) / 64, 4), 256, 0, stream>>>(x, W1, ft1b, N_NODES);
  eler_k<256><<<N_NODES, 256, 0, stream>>>(ft1b, al1, ar1, el1, er1);
  attw4_k<<<(N_NODES + 3) / 4, 256, 0, stream>>>(el1, er1, off, ssrc, wgt, rs);
  agg4_k<<<(N_NODES + 3) / 4, 256, 0, stream>>>(ft1b, wgt, rs, off, ssrc, b1, h1);

  // ---- layer 2 (H=1, D=64) ----
  gemm64<256, HID><<<dim3((N_NODES + 63) / 64, 1), 256, 0, stream>>>(h1, W2, ft2b, N_NODES);
  eler_k<64><<<N_NODES, 64, 0, stream>>>(ft2b, al2, ar2, el2, er2);
  attw1_k<<<(N_NODES + 3) / 4, 256, 0, stream>>>(el2, er2, off, ssrc, wgt, rs);
  agg1_k<<<(N_NODES + 3) / 4, 256, 0, stream>>>(ft2b, wgt, rs, off, ssrc, b2, out);
}

// Round 5
// 309.722 us; speedup vs baseline: 1.8167x; 1.1432x over previous
//
#include <hip/hip_runtime.h>
#include <hip/hip_bf16.h>
#include <math.h>

#define N_NODES 50000
#define N_EDGES 800000
#define IN_DIM 128
#define HID 64
#define HEADS 4

typedef unsigned short ushort_t;
typedef __attribute__((ext_vector_type(8))) short bf16x8;
typedef __attribute__((ext_vector_type(4))) float f32x4;

static __device__ __forceinline__ ushort_t f2bf(float f) {
  __hip_bfloat16 b = __float2bfloat16(f);
  return *(ushort_t*)&b;
}
static __device__ __forceinline__ float bflo(unsigned d) {
  union { unsigned u; float f; } c; c.u = d << 16; return c.f;
}
static __device__ __forceinline__ float bfhi(unsigned d) {
  union { unsigned u; float f; } c; c.u = d & 0xffff0000u; return c.f;
}
static __device__ __forceinline__ unsigned packbf(float lo, float hi) {
  return (unsigned)f2bf(lo) | ((unsigned)f2bf(hi) << 16);
}
static __device__ __forceinline__ float lrelu(float x) {
  return (x > 0.f) ? x : 0.01f * x;
}

// ---------------- fp32 -> bf16 conversion (x, W1, W2) ----------------
__global__ __launch_bounds__(256) void cvt_k(const float* __restrict__ x,
                                             const float* __restrict__ w1,
                                             const float* __restrict__ w2,
                                             ushort_t* __restrict__ xb,
                                             ushort_t* __restrict__ w1b,
                                             ushort_t* __restrict__ w2b) {
  constexpr int nx = N_NODES * IN_DIM / 4;
  constexpr int n1 = IN_DIM * 256 / 4;
  constexpr int n2 = 256 * 64 / 4;
  int i = blockIdx.x * 256 + threadIdx.x;
  const float4* s; ushort_t* d; int j;
  if (i < nx) { s = (const float4*)x; d = xb; j = i; }
  else if (i < nx + n1) { s = (const float4*)w1; d = w1b; j = i - nx; }
  else if (i < nx + n1 + n2) { s = (const float4*)w2; d = w2b; j = i - nx - n1; }
  else return;
  float4 v = s[j];
  ushort4 u;
  u.x = f2bf(v.x); u.y = f2bf(v.y); u.z = f2bf(v.z); u.w = f2bf(v.w);
  *(ushort4*)&d[j * 4] = u;
}

// ---------------- bf16 MFMA GEMM: C[M,NC] = A[M,K]*B[K,NC], all bf16, fp32 acc
// block: 256 thr = 4 waves; tile 128(M) x 64(N), BK=32.
// wave w owns rows [w*32, w*32+32): 2 row-tiles x 4 col-tiles of 16x16.
template<int K, int NC>
__global__ __launch_bounds__(256) void gemm_mfma(const ushort_t* __restrict__ A,
                                                 const ushort_t* __restrict__ B,
                                                 ushort_t* __restrict__ C, int M) {
  __shared__ ushort_t As[128][40];  // rows padded to 40 bf16 (80B) -> 2-way max
  __shared__ ushort_t Bs[64][40];   // stored TRANSPOSED: Bs[col][k]
  const int tid = threadIdx.x;
  const int m0 = blockIdx.x * 128;
  const int n0 = blockIdx.y * 64;
  const int w = tid >> 6, l = tid & 63;
  const int lr = l & 15, lk = l >> 4;  // frag row(col) and k-group
  f32x4 acc[2][4] = {};

  for (int k0 = 0; k0 < K; k0 += 32) {
    // stage A: 512 slots of 8 bf16; thread handles 2
    #pragma unroll
    for (int j = 0; j < 2; ++j) {
      int slot = tid + j * 256;
      int r = slot >> 2, kg = slot & 3;
      uint4 v = make_uint4(0, 0, 0, 0);
      if (m0 + r < M) v = *(const uint4*)&A[(size_t)(m0 + r) * K + k0 + kg * 8];
      *(uint4*)&As[r][kg * 8] = v;
    }
    // stage B transposed: thread: k=tid>>3, c8=(tid&7)*8
    {
      int k = tid >> 3, c8 = (tid & 7) * 8;
      uint4 v = *(const uint4*)&B[(size_t)(k0 + k) * NC + n0 + c8];
      const ushort_t* pv = (const ushort_t*)&v;
      #pragma unroll
      for (int j = 0; j < 8; ++j) Bs[c8 + j][k] = pv[j];
    }
    __syncthreads();
    bf16x8 a0 = *(const bf16x8*)&As[w * 32 + lr][lk * 8];
    bf16x8 a1 = *(const bf16x8*)&As[w * 32 + 16 + lr][lk * 8];
    #pragma unroll
    for (int ct = 0; ct < 4; ++ct) {
      bf16x8 b = *(const bf16x8*)&Bs[ct * 16 + lr][lk * 8];
      acc[0][ct] = __builtin_amdgcn_mfma_f32_16x16x32_bf16(a0, b, acc[0][ct], 0, 0, 0);
      acc[1][ct] = __builtin_amdgcn_mfma_f32_16x16x32_bf16(a1, b, acc[1][ct], 0, 0, 0);
    }
    __syncthreads();
  }
  // epilogue: D col = lane&15, row = (lane>>4)*4 + j  [m89 verified layout]
  #pragma unroll
  for (int rt = 0; rt < 2; ++rt)
    #pragma unroll
    for (int ct = 0; ct < 4; ++ct)
      #pragma unroll
      for (int j = 0; j < 4; ++j) {
        int row = m0 + w * 32 + rt * 16 + lk * 4 + j;
        if (row < M) C[(size_t)row * NC + n0 + ct * 16 + lr] = f2bf(acc[rt][ct][j]);
      }
}

// ---------------- el/er: per-node attention dot products (bf16 ft) -----------
template<int HD>
__global__ void eler_k(const ushort_t* __restrict__ ft, const float* __restrict__ al,
                       const float* __restrict__ ar, float* __restrict__ el,
                       float* __restrict__ er) {
  int n = blockIdx.x;
  int t = threadIdx.x;
  float f = bflo((unsigned)ft[(size_t)n * HD + t]);
  float vl = f * al[t], vr = f * ar[t];
  #pragma unroll
  for (int s = 32; s; s >>= 1) { vl += __shfl_down(vl, s); vr += __shfl_down(vr, s); }
  if ((t & 63) == 0) {
    int h = t >> 6;
    el[n * (HD / 64) + h] = vl;
    er[n * (HD / 64) + h] = vr;
  }
}

// ---------------- CSR build (histogram + scan + place) ----------------
__global__ void hist_k(const int* __restrict__ dst, int* __restrict__ cnt) {
  int e = blockIdx.x * 256 + threadIdx.x;
  if (e < N_EDGES) atomicAdd(&cnt[dst[e]], 1);
}

__global__ void scan1_k(const int* __restrict__ cnt, int* __restrict__ off,
                        int* __restrict__ bsum) {
  __shared__ int lds[1024];
  int tid = threadIdx.x;
  int i = blockIdx.x * 1024 + tid;
  int v = (i < N_NODES) ? cnt[i] : 0;
  lds[tid] = v;
  __syncthreads();
  for (int s = 1; s < 1024; s <<= 1) {
    int t = (tid >= s) ? lds[tid - s] : 0;
    __syncthreads();
    lds[tid] += t;
    __syncthreads();
  }
  if (i < N_NODES) off[i] = lds[tid] - v;
  if (tid == 1023) bsum[blockIdx.x] = lds[1023];
}

__global__ void scan2_k(int* __restrict__ bsum, int nb) {
  int lane = threadIdx.x;
  int v = (lane < nb) ? bsum[lane] : 0;
  int orig = v;
  for (int s = 1; s < 64; s <<= 1) { int t = __shfl_up(v, s); if (lane >= s) v += t; }
  if (lane < nb) bsum[lane] = v - orig;
}

__global__ void scan3_k(int* __restrict__ off, const int* __restrict__ bsum) {
  int i = blockIdx.x * 1024 + threadIdx.x;
  if (i < N_NODES) off[i] += bsum[blockIdx.x];
  if (i == 0) off[N_NODES] = N_EDGES;
}

__global__ void place_k(const int* __restrict__ src, const int* __restrict__ dst,
                        const int* __restrict__ off, int* __restrict__ cnt,
                        int* __restrict__ ssrc) {
  int e = blockIdx.x * 256 + threadIdx.x;
  if (e < N_EDGES) {
    int d = dst[e];
    int p = atomicAdd(&cnt[d], 1);
    ssrc[off[d] + p] = src[e];
  }
}

// ---- attention weights, H=4: one wave per node, single gather pass ----
__global__ __launch_bounds__(256) void attw4_k(const float* __restrict__ el,
                                               const float* __restrict__ er,
                                               const int* __restrict__ off,
                                               const int* __restrict__ ssrc,
                                               float* __restrict__ wgt,
                                               float* __restrict__ rs) {
  int n = (blockIdx.x * 256 + threadIdx.x) >> 6;
  int lane = threadIdx.x & 63;
  if (n >= N_NODES) return;
  int s0 = off[n], s1 = off[n + 1];
  if (s0 >= s1) {
    if (lane == 0) ((float4*)rs)[n] = make_float4(0.f, 0.f, 0.f, 0.f);
    return;
  }
  const float4* el4 = (const float4*)el;
  float4 erv = ((const float4*)er)[n];
  float4 m = make_float4(-INFINITY, -INFINITY, -INFINITY, -INFINITY);
  float4 x0 = m;
  int i0 = s0 + lane;
  bool v0 = (i0 < s1);
  if (v0) {
    int s = ssrc[i0];
    float4 e = el4[s];
    x0.x = lrelu(e.x + erv.x); x0.y = lrelu(e.y + erv.y);
    x0.z = lrelu(e.z + erv.z); x0.w = lrelu(e.w + erv.w);
    m = x0;
  }
  for (int i = i0 + 64; i < s1; i += 64) {
    int s = ssrc[i];
    float4 e = el4[s];
    m.x = fmaxf(m.x, lrelu(e.x + erv.x)); m.y = fmaxf(m.y, lrelu(e.y + erv.y));
    m.z = fmaxf(m.z, lrelu(e.z + erv.z)); m.w = fmaxf(m.w, lrelu(e.w + erv.w));
  }
  #pragma unroll
  for (int o = 32; o; o >>= 1) {
    m.x = fmaxf(m.x, __shfl_xor(m.x, o)); m.y = fmaxf(m.y, __shfl_xor(m.y, o));
    m.z = fmaxf(m.z, __shfl_xor(m.z, o)); m.w = fmaxf(m.w, __shfl_xor(m.w, o));
  }
  float4 sum = make_float4(0.f, 0.f, 0.f, 0.f);
  if (v0) {
    float4 ex;
    ex.x = __expf(x0.x - m.x); ex.y = __expf(x0.y - m.y);
    ex.z = __expf(x0.z - m.z); ex.w = __expf(x0.w - m.w);
    sum = ex;
    ((float4*)wgt)[i0] = ex;
  }
  for (int i = i0 + 64; i < s1; i += 64) {
    int s = ssrc[i];
    float4 e = el4[s];
    float4 ex;
    ex.x = __expf(lrelu(e.x + erv.x) - m.x); ex.y = __expf(lrelu(e.y + erv.y) - m.y);
    ex.z = __expf(lrelu(e.z + erv.z) - m.z); ex.w = __expf(lrelu(e.w + erv.w) - m.w);
    sum.x += ex.x; sum.y += ex.y; sum.z += ex.z; sum.w += ex.w;
    ((float4*)wgt)[i] = ex;
  }
  #pragma unroll
  for (int o = 32; o; o >>= 1) {
    sum.x += __shfl_xor(sum.x, o); sum.y += __shfl_xor(sum.y, o);
    sum.z += __shfl_xor(sum.z, o); sum.w += __shfl_xor(sum.w, o);
  }
  if (lane == 0)
    ((float4*)rs)[n] = make_float4(1.f / sum.x, 1.f / sum.y, 1.f / sum.z, 1.f / sum.w);
}

// ---- attention weights, H=1 ----
__global__ __launch_bounds__(256) void attw1_k(const float* __restrict__ el,
                                               const float* __restrict__ er,
                                               const int* __restrict__ off,
                                               const int* __restrict__ ssrc,
                                               float* __restrict__ wgt,
                                               float* __restrict__ rs) {
  int n = (blockIdx.x * 256 + threadIdx.x) >> 6;
  int lane = threadIdx.x & 63;
  if (n >= N_NODES) return;
  int s0 = off[n], s1 = off[n + 1];
  if (s0 >= s1) {
    if (lane == 0) rs[n] = 0.f;
    return;
  }
  float erv = er[n];
  float m = -INFINITY, x0 = -INFINITY;
  int i0 = s0 + lane;
  bool v0 = (i0 < s1);
  if (v0) { x0 = lrelu(el[ssrc[i0]] + erv); m = x0; }
  for (int i = i0 + 64; i < s1; i += 64) m = fmaxf(m, lrelu(el[ssrc[i]] + erv));
  #pragma unroll
  for (int o = 32; o; o >>= 1) m = fmaxf(m, __shfl_xor(m, o));
  float sum = 0.f;
  if (v0) { float ex = __expf(x0 - m); sum = ex; wgt[i0] = ex; }
  for (int i = i0 + 64; i < s1; i += 64) {
    float ex = __expf(lrelu(el[ssrc[i]] + erv) - m);
    sum += ex;
    wgt[i] = ex;
  }
  #pragma unroll
  for (int o = 32; o; o >>= 1) sum += __shfl_xor(sum, o);
  if (lane == 0) rs[n] = 1.f / sum;
}

// ---------------- layer-1 aggregation: bf16 in, bf16 out, 2 edges per wave ---
__global__ __launch_bounds__(256) void agg4_k(const ushort_t* __restrict__ ftb,
                                              const float* __restrict__ wgt,
                                              const float* __restrict__ rs,
                                              const int* __restrict__ off,
                                              const int* __restrict__ ssrc,
                                              const float* __restrict__ bias,
                                              ushort_t* __restrict__ outb) {
  int n = (blockIdx.x * 256 + threadIdx.x) >> 6;
  int lane = threadIdx.x & 63;
  if (n >= N_NODES) return;
  int s0 = off[n], s1 = off[n + 1];
  int half = lane >> 5, sl = lane & 31;
  int head = sl >> 3;
  float acc[8] = {};
  #pragma unroll 4
  for (int i = s0; i < s1; i += 2) {
    int e = i + half;
    if (e < s1) {
      int s = ssrc[e];
      float w = wgt[e * 4 + head];
      uint4 u = *(const uint4*)&ftb[s * 256 + sl * 8];  // 16B = 8 bf16
      acc[0] = fmaf(w, bflo(u.x), acc[0]);
      acc[1] = fmaf(w, bfhi(u.x), acc[1]);
      acc[2] = fmaf(w, bflo(u.y), acc[2]);
      acc[3] = fmaf(w, bfhi(u.y), acc[3]);
      acc[4] = fmaf(w, bflo(u.z), acc[4]);
      acc[5] = fmaf(w, bfhi(u.z), acc[5]);
      acc[6] = fmaf(w, bflo(u.w), acc[6]);
      acc[7] = fmaf(w, bfhi(u.w), acc[7]);
    }
  }
  #pragma unroll
  for (int j = 0; j < 8; ++j) acc[j] += __shfl_xor(acc[j], 32);
  if (half == 0) {
    float rsv = rs[n * 4 + head];
    float4 b0 = ((const float4*)bias)[sl * 2];
    float4 b1 = ((const float4*)bias)[sl * 2 + 1];
    float o[8] = {fmaf(acc[0], rsv, b0.x), fmaf(acc[1], rsv, b0.y),
                  fmaf(acc[2], rsv, b0.z), fmaf(acc[3], rsv, b0.w),
                  fmaf(acc[4], rsv, b1.x), fmaf(acc[5], rsv, b1.y),
                  fmaf(acc[6], rsv, b1.z), fmaf(acc[7], rsv, b1.w)};
    #pragma unroll
    for (int j = 0; j < 8; ++j) o[j] = (o[j] > 0.f) ? o[j] : expm1f(o[j]);
    uint4 p;
    p.x = packbf(o[0], o[1]); p.y = packbf(o[2], o[3]);
    p.z = packbf(o[4], o[5]); p.w = packbf(o[6], o[7]);
    *(uint4*)&outb[n * 256 + sl * 8] = p;
  }
}

// ---------------- layer-2 aggregation: bf16 in, fp32 out, 8 edges/iter -------
__global__ __launch_bounds__(256) void agg1_k(const ushort_t* __restrict__ ftb,
                                              const float* __restrict__ wgt,
                                              const float* __restrict__ rs,
                                              const int* __restrict__ off,
                                              const int* __restrict__ ssrc,
                                              const float* __restrict__ bias,
                                              float* __restrict__ out) {
  int n = (blockIdx.x * 256 + threadIdx.x) >> 6;
  int lane = threadIdx.x & 63;
  if (n >= N_NODES) return;
  int s0 = off[n], s1 = off[n + 1];
  int g = lane >> 3, c = lane & 7;
  float acc[8] = {};
  #pragma unroll 2
  for (int i = s0; i < s1; i += 8) {
    int e = i + g;
    if (e < s1) {
      int s = ssrc[e];
      float w = wgt[e];
      uint4 u = *(const uint4*)&ftb[s * 64 + c * 8];
      acc[0] = fmaf(w, bflo(u.x), acc[0]);
      acc[1] = fmaf(w, bfhi(u.x), acc[1]);
      acc[2] = fmaf(w, bflo(u.y), acc[2]);
      acc[3] = fmaf(w, bfhi(u.y), acc[3]);
      acc[4] = fmaf(w, bflo(u.z), acc[4]);
      acc[5] = fmaf(w, bfhi(u.z), acc[5]);
      acc[6] = fmaf(w, bflo(u.w), acc[6]);
      acc[7] = fmaf(w, bfhi(u.w), acc[7]);
    }
  }
  #pragma unroll
  for (int o = 8; o <= 32; o <<= 1)
    #pragma unroll
    for (int j = 0; j < 8; ++j) acc[j] += __shfl_xor(acc[j], o);
  if (g == 0) {
    float rsv = rs[n];
    float4 b0 = ((const float4*)bias)[c * 2];
    float4 b1 = ((const float4*)bias)[c * 2 + 1];
    float o[8] = {fmaf(acc[0], rsv, b0.x), fmaf(acc[1], rsv, b0.y),
                  fmaf(acc[2], rsv, b0.z), fmaf(acc[3], rsv, b0.w),
                  fmaf(acc[4], rsv, b1.x), fmaf(acc[5], rsv, b1.y),
                  fmaf(acc[6], rsv, b1.z), fmaf(acc[7], rsv, b1.w)};
    #pragma unroll
    for (int j = 0; j < 8; ++j) o[j] = (o[j] > 0.f) ? o[j] : expm1f(o[j]);
    float4* out4 = (float4*)out;
    out4[(size_t)n * 16 + c * 2]     = make_float4(o[0], o[1], o[2], o[3]);
    out4[(size_t)n * 16 + c * 2 + 1] = make_float4(o[4], o[5], o[6], o[7]);
  }
}

extern "C" void kernel_launch(void* const* d_in, const int* in_sizes, int n_in,
                              void* d_out, int out_size, void* d_ws, size_t ws_size,
                              hipStream_t stream) {
  const float* x   = (const float*)d_in[0];
  const int*   src = (const int*)d_in[1];
  const int*   dst = (const int*)d_in[2];
  const float* W1  = (const float*)d_in[3];
  const float* al1 = (const float*)d_in[4];
  const float* ar1 = (const float*)d_in[5];
  const float* b1  = (const float*)d_in[6];
  const float* W2  = (const float*)d_in[7];
  const float* al2 = (const float*)d_in[8];
  const float* ar2 = (const float*)d_in[9];
  const float* b2  = (const float*)d_in[10];
  float* out = (float*)d_out;

  char* ws = (char*)d_ws;
  size_t wo = 0;
  auto alloc = [&](size_t b) { void* p = ws + wo; wo = (wo + b + 255) & ~(size_t)255; return p; };
  ushort_t* ft1b = (ushort_t*)alloc((size_t)N_NODES * 256 * 2);  // reused as ft2b
  ushort_t* h1b  = (ushort_t*)alloc((size_t)N_NODES * 256 * 2);
  ushort_t* xb   = (ushort_t*)alloc((size_t)N_NODES * IN_DIM * 2);
  ushort_t* w1b  = (ushort_t*)alloc((size_t)IN_DIM * 256 * 2);
  ushort_t* w2b  = (ushort_t*)alloc((size_t)256 * 64 * 2);
  float* el1 = (float*)alloc((size_t)N_NODES * 4 * 4);
  float* er1 = (float*)alloc((size_t)N_NODES * 4 * 4);
  float* rs  = (float*)alloc((size_t)N_NODES * 4 * 4);
  int*   off = (int*)alloc((size_t)(N_NODES + 1) * 4);
  int*   cnt = (int*)alloc((size_t)N_NODES * 4);
  int*   bsum= (int*)alloc(256);
  int*   ssrc= (int*)alloc((size_t)N_EDGES * 4);
  float* wgt = (float*)alloc((size_t)N_EDGES * 4 * 4);
  ushort_t* ft2b = ft1b;
  float* el2 = el1, *er2 = er1;

  // ---- bf16 conversion of GEMM operands ----
  constexpr int ncvt = (N_NODES * IN_DIM + IN_DIM * 256 + 256 * 64) / 4;
  cvt_k<<<(ncvt + 255) / 256, 256, 0, stream>>>(x, W1, W2, xb, w1b, w2b);

  // ---- CSR by dst (once; same graph both layers) ----
  hipMemsetAsync(cnt, 0, (size_t)N_NODES * 4, stream);
  hist_k<<<(N_EDGES + 255) / 256, 256, 0, stream>>>(dst, cnt);
  int nb = (N_NODES + 1023) / 1024;
  scan1_k<<<nb, 1024, 0, stream>>>(cnt, off, bsum);
  scan2_k<<<1, 64, 0, stream>>>(bsum, nb);
  scan3_k<<<nb, 1024, 0, stream>>>(off, bsum);
  hipMemsetAsync(cnt, 0, (size_t)N_NODES * 4, stream);
  place_k<<<(N_EDGES + 255) / 256, 256, 0, stream>>>(src, dst, off, cnt, ssrc);

  // ---- layer 1 (H=4, D=64) ----
  gemm_mfma<IN_DIM, 256><<<dim3((N_NODES + 127) / 128, 4), 256, 0, stream>>>(xb, w1b, ft1b, N_NODES);
  eler_k<256><<<N_NODES, 256, 0, stream>>>(ft1b, al1, ar1, el1, er1);
  attw4_k<<<(N_NODES + 3) / 4, 256, 0, stream>>>(el1, er1, off, ssrc, wgt, rs);
  agg4_k<<<(N_NODES + 3) / 4, 256, 0, stream>>>(ft1b, wgt, rs, off, ssrc, b1, h1b);

  // ---- layer 2 (H=1, D=64) ----
  gemm_mfma<256, HID><<<dim3((N_NODES + 127) / 128, 1), 256, 0, stream>>>(h1b, w2b, ft2b, N_NODES);
  eler_k<64><<<N_NODES, 64, 0, stream>>>(ft2b, al2, ar2, el2, er2);
  attw1_k<<<(N_NODES + 3) / 4, 256, 0, stream>>>(el2, er2, off, ssrc, wgt, rs);
  agg1_k<<<(N_NODES + 3) / 4, 256, 0, stream>>>(ft2b, wgt, rs, off, ssrc, b2, out);
}